// Round 8
// baseline (307.991 us; speedup 1.0000x reference)
//
#include <hip/hip_runtime.h>
#include <hip/hip_bf16.h>
#include <hip/hip_cooperative_groups.h>

namespace cg = cooperative_groups;

#define B_    2048
#define OBS_  1024
#define A_    512
#define NC    128      // [actor 64 | critic 64] hidden cols

typedef __attribute__((ext_vector_type(8))) short bf16x8;
typedef __attribute__((ext_vector_type(4))) float f32x4;

__device__ __forceinline__ float fast_tanh(float x) {
    return 1.0f - 2.0f / (__expf(2.0f * x) + 1.0f);
}

__device__ __forceinline__ unsigned short rne_bf16(float f) {
    union { float f; unsigned u; } v; v.f = f;
    unsigned u = v.u;
    return (unsigned short)((u + 0x7FFFu + ((u >> 16) & 1u)) >> 16);
}

__device__ __forceinline__ unsigned pack_bf16(float lo, float hi) {
    return (unsigned)rne_bf16(lo) | ((unsigned)rne_bf16(hi) << 16);
}

__device__ __forceinline__ short to_bf16(float f) {
    __hip_bfloat16 h = __float2bfloat16(f);   // RNE
    return *reinterpret_cast<short*>(&h);
}

// broadcast register value from lane k (compile-time k) via SGPR, no LDS
#define RL(x, k) __int_as_float(__builtin_amdgcn_readlane(__float_as_int(x), (k)))

struct KParams {
    const float* x;
    const int*   action_types;
    const int*   action_counts;
    const int*   action;
    const float* emb;
    const float* W1;  const float* b1;
    const float* W2;  const float* b2;
    const float* Wf;  const float* We;  const float* ba;
    const float* Wo;  const float* bo;
    const float* Wc1; const float* bc1;
    const float* Wc2; const float* bc2;
    const float* Wc3; const float* bc3;
    float* out;
    unsigned short* Wfrag;   // [32][8][64][8] bf16
    float* embWeT;           // [64][64]
    float* partials;         // [4][2048][128] f32
};

// Single cooperative kernel: 512 blocks x 256 threads, 3 phases + 2 grid syncs.
__global__ __launch_bounds__(256, 2) void k_all(KParams p) {
    __shared__ unsigned sW2p[32][64];
    __shared__ unsigned sWfp[32][64];
    __shared__ unsigned sWc2p[32][64];
    __shared__ unsigned sVTp[32][64];
    __shared__ int scnt[4][64];

    const int tid = threadIdx.x;
    const int bid = blockIdx.x;
    cg::grid_group grid = cg::this_grid();

    // ---------------- Phase A: weight prep (k0) ----------------
    {
        int gid   = bid * 256 + tid;          // 0..131071, exactly Wfrag
        int i     = gid & 7;
        int lane  = (gid >> 3) & 63;
        int ntile = (gid >> 9) & 7;
        int ks    = gid >> 12;
        int k = ks * 32 + ((lane >> 4) << 3) + i;
        int n = ntile * 16 + (lane & 15);
        float wv = (n < 64) ? p.W1[(size_t)k * 64 + n] : p.Wc1[(size_t)k * 64 + (n - 64)];
        p.Wfrag[gid] = rne_bf16(wv);
        if (bid < 16) {
            int idx = bid * 256 + tid;        // 0..4095
            int h = idx >> 6, t = idx & 63;
            float s = 0.f;
            #pragma unroll
            for (int e = 0; e < 16; ++e) s += p.emb[t * 16 + e] * p.We[e * 64 + h];
            p.embWeT[idx] = s;
        }
    }
    __threadfence();
    grid.sync();
    __threadfence();

    // ---------------- Phase B: MFMA GEMM, 4-way K-split (k1) ----------------
    {
        const int w   = tid >> 6;
        const int l   = tid & 63;
        const int mb     = bid >> 2;
        const int kslice = bid & 3;

        const int row  = mb * 16 + (l & 15);
        const int kgrp = (l >> 4) << 3;
        const float* xrow = p.x + (size_t)row * OBS_ + kslice * 256;
        const bf16x8* Wf8 = (const bf16x8*)p.Wfrag;

        f32x4 acc0 = {0.f, 0.f, 0.f, 0.f};
        f32x4 acc1 = {0.f, 0.f, 0.f, 0.f};
        const int nt0 = w * 2, nt1 = w * 2 + 1;

        #pragma unroll
        for (int ks = 0; ks < 8; ++ks) {
            const float4* xp = (const float4*)(xrow + ks * 32 + kgrp);
            float4 a0 = xp[0];
            float4 a1 = xp[1];
            bf16x8 av;
            av[0] = to_bf16(a0.x); av[1] = to_bf16(a0.y);
            av[2] = to_bf16(a0.z); av[3] = to_bf16(a0.w);
            av[4] = to_bf16(a1.x); av[5] = to_bf16(a1.y);
            av[6] = to_bf16(a1.z); av[7] = to_bf16(a1.w);
            const int kg = kslice * 8 + ks;
            bf16x8 bv0 = Wf8[(kg * 8 + nt0) * 64 + l];
            bf16x8 bv1 = Wf8[(kg * 8 + nt1) * 64 + l];
            acc0 = __builtin_amdgcn_mfma_f32_16x16x32_bf16(av, bv0, acc0, 0, 0, 0);
            acc1 = __builtin_amdgcn_mfma_f32_16x16x32_bf16(av, bv1, acc1, 0, 0, 0);
        }

        float* pbase = p.partials + (size_t)kslice * B_ * NC;
        const int rbase = mb * 16 + ((l >> 4) << 2);
        {
            int col = nt0 * 16 + (l & 15);
            #pragma unroll
            for (int r = 0; r < 4; ++r)
                pbase[(size_t)(rbase + r) * NC + col] = acc0[r];
        }
        {
            int col = nt1 * 16 + (l & 15);
            #pragma unroll
            for (int r = 0; r < 4; ++r)
                pbase[(size_t)(rbase + r) * NC + col] = acc1[r];
        }
    }
    __threadfence();
    grid.sync();
    __threadfence();

    // ---------------- Phase C: fused head (k2) ----------------
    {
        #pragma unroll
        for (int i = 0; i < 8; ++i) {
            int idx = tid + i * 256;        // 0..2047
            int rp = idx >> 6, hh = idx & 63;
            sW2p [rp][hh] = pack_bf16(p.W2 [(2 * rp) * 64 + hh], p.W2 [(2 * rp + 1) * 64 + hh]);
            sWfp [rp][hh] = pack_bf16(p.Wf [(2 * rp) * 64 + hh], p.Wf [(2 * rp + 1) * 64 + hh]);
            sWc2p[rp][hh] = pack_bf16(p.Wc2[(2 * rp) * 64 + hh], p.Wc2[(2 * rp + 1) * 64 + hh]);
            sVTp [rp][hh] = pack_bf16(p.embWeT[(2 * rp) * 64 + hh], p.embWeT[(2 * rp + 1) * 64 + hh]);
        }
        scnt[tid >> 6][tid & 63] = 0;
        __syncthreads();

        const int lane = tid & 63;
        const int wid  = tid >> 6;
        const int b    = bid * 4 + wid;

        const float* pa = p.partials + (size_t)b * NC + lane;
        const float* pc = pa + 64;
        float h1v = pa[0] + pa[1 * B_ * NC] + pa[2 * B_ * NC] + pa[3 * B_ * NC];
        float c1v = pc[0] + pc[1 * B_ * NC] + pc[2 * B_ * NC] + pc[3 * B_ * NC];
        h1v = fast_tanh(h1v + p.b1[lane]);
        c1v = fast_tanh(c1v + p.bc1[lane]);
        const int* at_row = p.action_types + (size_t)b * A_;
        const int count = p.action_counts[b];
        const int base = lane * 8;
        int4 q0 = *reinterpret_cast<const int4*>(at_row + base);
        int4 q1 = *reinterpret_cast<const int4*>(at_row + base + 4);
        const int a_star = p.action[b];
        const int t_star = at_row[a_star] & 63;

        // feats[h] = tanh(sum_k h1[k]*W2[k][h] + b2[h])
        float f = p.b2[lane];
        #pragma unroll
        for (int kp = 0; kp < 32; ++kp) {
            unsigned pw = sW2p[kp][lane];
            f += RL(h1v, 2 * kp)     * __uint_as_float(pw << 16);
            f += RL(h1v, 2 * kp + 1) * __uint_as_float(pw & 0xffff0000u);
        }
        f = fast_tanh(f);

        // u[h] = sum_k feats[k]*Wf[k][h] + ba[h]
        float u = p.ba[lane];
        #pragma unroll
        for (int kp = 0; kp < 32; ++kp) {
            unsigned pw = sWfp[kp][lane];
            u += RL(f, 2 * kp)     * __uint_as_float(pw << 16);
            u += RL(f, 2 * kp + 1) * __uint_as_float(pw & 0xffff0000u);
        }

        // critic: cc = tanh(c1@Wc2+bc2); value = cc.Wc3 + bc3
        float cc = p.bc2[lane];
        #pragma unroll
        for (int kp = 0; kp < 32; ++kp) {
            unsigned pw = sWc2p[kp][lane];
            cc += RL(c1v, 2 * kp)     * __uint_as_float(pw << 16);
            cc += RL(c1v, 2 * kp + 1) * __uint_as_float(pw & 0xffff0000u);
        }
        cc = fast_tanh(cc);
        float pv = cc * p.Wc3[lane];
        #pragma unroll
        for (int off = 32; off > 0; off >>= 1) pv += __shfl_xor(pv, off);
        const float value = pv + p.bc3[0];

        // score-per-type: lane = t
        float s = p.bo[0];
        #pragma unroll
        for (int hp = 0; hp < 32; ++hp) {
            unsigned pvv = sVTp[hp][lane];
            s += fast_tanh(RL(u, 2 * hp)     + __uint_as_float(pvv << 16))         * p.Wo[2 * hp];
            s += fast_tanh(RL(u, 2 * hp + 1) + __uint_as_float(pvv & 0xffff0000u)) * p.Wo[2 * hp + 1];
        }

        // histogram of valid action types (wave-private)
        int* cptr = scnt[wid];
        if (base + 0 < count) atomicAdd(&cptr[q0.x & 63], 1);
        if (base + 1 < count) atomicAdd(&cptr[q0.y & 63], 1);
        if (base + 2 < count) atomicAdd(&cptr[q0.z & 63], 1);
        if (base + 3 < count) atomicAdd(&cptr[q0.w & 63], 1);
        if (base + 4 < count) atomicAdd(&cptr[q1.x & 63], 1);
        if (base + 5 < count) atomicAdd(&cptr[q1.y & 63], 1);
        if (base + 6 < count) atomicAdd(&cptr[q1.z & 63], 1);
        if (base + 7 < count) atomicAdd(&cptr[q1.w & 63], 1);

        // softmax stats over 64 types weighted by counts
        const int cv = cptr[lane];
        float mval = (cv > 0) ? s : -3.0e38f;
        #pragma unroll
        for (int off = 32; off > 0; off >>= 1) mval = fmaxf(mval, __shfl_xor(mval, off));
        const float e  = (float)cv * __expf(s - mval);
        float se = e, sd = e * s;
        #pragma unroll
        for (int off = 32; off > 0; off >>= 1) {
            se += __shfl_xor(se, off);
            sd += __shfl_xor(sd, off);
        }
        const float logZ    = mval + __logf(se);
        const float entropy = logZ - sd / se;
        const float logp    = __shfl(s, t_star) - logZ;

        if (lane == 0) {
            p.out[b * 3 + 0] = logp;
            p.out[b * 3 + 1] = entropy;
            p.out[b * 3 + 2] = value;
        }
    }
}

extern "C" void kernel_launch(void* const* d_in, const int* in_sizes, int n_in,
                              void* d_out, int out_size, void* d_ws, size_t ws_size,
                              hipStream_t stream) {
    unsigned char* ws = (unsigned char*)d_ws;

    KParams p;
    p.x             = (const float*)d_in[0];
    p.action_types  = (const int*)  d_in[1];
    p.action_counts = (const int*)  d_in[2];
    p.action        = (const int*)  d_in[3];
    p.emb           = (const float*)d_in[4];
    p.W1  = (const float*)d_in[5];  p.b1  = (const float*)d_in[6];
    p.W2  = (const float*)d_in[7];  p.b2  = (const float*)d_in[8];
    p.Wf  = (const float*)d_in[9];  p.We  = (const float*)d_in[10];
    p.ba  = (const float*)d_in[11]; p.Wo  = (const float*)d_in[12];
    p.bo  = (const float*)d_in[13];
    p.Wc1 = (const float*)d_in[14]; p.bc1 = (const float*)d_in[15];
    p.Wc2 = (const float*)d_in[16]; p.bc2 = (const float*)d_in[17];
    p.Wc3 = (const float*)d_in[18]; p.bc3 = (const float*)d_in[19];
    p.out = (float*)d_out;
    p.Wfrag    = (unsigned short*)ws;                        // 256 KB
    p.embWeT   = (float*)(ws + 262144);                      // 16 KB
    p.partials = (float*)(ws + 262144 + 16384);              // 4 MB

    void* args[] = { (void*)&p };
    hipLaunchCooperativeKernel(reinterpret_cast<void*>(k_all),
                               dim3(512), dim3(256), args, 0, stream);
}

// Round 9
// 28.036 us; speedup vs baseline: 10.9857x; 10.9857x over previous
//
#include <hip/hip_runtime.h>
#include <hip/hip_bf16.h>

#define B_    2048
#define OBS_  1024
#define A_    512
#define NC    128      // [actor 64 | critic 64] hidden cols
#define NSLICE 8       // K-split
#define PADK  136      // halfwords per wT row (128 + 8 pad)

typedef __attribute__((ext_vector_type(8))) short bf16x8;
typedef __attribute__((ext_vector_type(4))) float f32x4;

__device__ __forceinline__ float fast_tanh(float x) {
    return 1.0f - 2.0f / (__expf(2.0f * x) + 1.0f);
}

__device__ __forceinline__ unsigned short rne_bf16(float f) {
    union { float f; unsigned u; } v; v.f = f;
    unsigned u = v.u;
    return (unsigned short)((u + 0x7FFFu + ((u >> 16) & 1u)) >> 16);
}

__device__ __forceinline__ unsigned pack_bf16(float lo, float hi) {
    return (unsigned)rne_bf16(lo) | ((unsigned)rne_bf16(hi) << 16);
}

__device__ __forceinline__ short to_bf16(float f) {
    __hip_bfloat16 h = __float2bfloat16(f);   // RNE
    return *reinterpret_cast<short*>(&h);
}

// broadcast register value from lane k (compile-time k) via SGPR, no LDS
#define RL(x, k) __int_as_float(__builtin_amdgcn_readlane(__float_as_int(x), (k)))

// ---------------- Kernel 1: self-contained MFMA GEMM, 8-way K-split -----------
// grid 1024: mb = bid>>3 (16-row tile), kslice = bid&7 (128 K each)
// Per block: stage W-slice fp32->bf16 into transposed LDS wT[n][kk] (one
// ds_read_b128 per B-fragment), MFMA, write fp32 partials.
// Blocks 0..15 additionally compute embWeT (consumed by k2 next launch).
__global__ __launch_bounds__(256) void k1_mfma(
        const float* __restrict__ x, const float* __restrict__ W1,
        const float* __restrict__ Wc1, const float* __restrict__ emb,
        const float* __restrict__ We, float* __restrict__ partials,
        float* __restrict__ embWeT) {
    __shared__ unsigned short wT[128 * PADK];   // 34.8 KB
    const int tid    = threadIdx.x;
    const int mb     = blockIdx.x >> 3;
    const int kslice = blockIdx.x & 7;
    const int k0     = kslice * 128;

    // ---- stage W[k0..k0+128)[0..128) -> wT[n][kk] bf16 ----
    {
        const int n  = tid & 127;
        const int th = tid >> 7;                 // 0..1
        const float* src = (n < 64) ? (W1 + n) : (Wc1 + (n - 64));
        #pragma unroll
        for (int gg = 0; gg < 16; ++gg) {
            int kq = gg * 2 + th;                // 0..31
            int k  = k0 + kq * 4;
            float w0 = src[(size_t)(k + 0) * 64];
            float w1 = src[(size_t)(k + 1) * 64];
            float w2 = src[(size_t)(k + 2) * 64];
            float w3 = src[(size_t)(k + 3) * 64];
            unsigned long long v = (unsigned long long)pack_bf16(w0, w1)
                                 | ((unsigned long long)pack_bf16(w2, w3) << 32);
            *reinterpret_cast<unsigned long long*>(&wT[n * PADK + kq * 4]) = v;
        }
    }
    __syncthreads();

    // ---- MFMA: 4 K-iters, 2 ntiles per wave ----
    const int w = tid >> 6;
    const int l = tid & 63;
    const int c = l & 15;
    const int g = l >> 4;

    const float* xrow = x + (size_t)(mb * 16 + c) * OBS_ + k0 + g * 8;
    const int nt0 = 2 * w, nt1 = 2 * w + 1;
    const unsigned short* bp0 = &wT[(nt0 * 16 + c) * PADK + g * 8];
    const unsigned short* bp1 = &wT[(nt1 * 16 + c) * PADK + g * 8];

    f32x4 acc0 = {0.f, 0.f, 0.f, 0.f};
    f32x4 acc1 = {0.f, 0.f, 0.f, 0.f};
    #pragma unroll
    for (int ks = 0; ks < 4; ++ks) {
        const float4* xp = (const float4*)(xrow + ks * 32);
        float4 a0 = xp[0];
        float4 a1 = xp[1];
        bf16x8 av;
        av[0] = to_bf16(a0.x); av[1] = to_bf16(a0.y);
        av[2] = to_bf16(a0.z); av[3] = to_bf16(a0.w);
        av[4] = to_bf16(a1.x); av[5] = to_bf16(a1.y);
        av[6] = to_bf16(a1.z); av[7] = to_bf16(a1.w);
        bf16x8 bv0 = *(const bf16x8*)(bp0 + ks * 32);
        bf16x8 bv1 = *(const bf16x8*)(bp1 + ks * 32);
        acc0 = __builtin_amdgcn_mfma_f32_16x16x32_bf16(av, bv0, acc0, 0, 0, 0);
        acc1 = __builtin_amdgcn_mfma_f32_16x16x32_bf16(av, bv1, acc1, 0, 0, 0);
    }

    // C/D layout: col = lane&15, row = (lane>>4)*4 + reg
    float* pbase = partials + (size_t)kslice * B_ * NC;
    const int rbase = mb * 16 + g * 4;
    {
        int col = nt0 * 16 + c;
        #pragma unroll
        for (int r = 0; r < 4; ++r)
            pbase[(size_t)(rbase + r) * NC + col] = acc0[r];
    }
    {
        int col = nt1 * 16 + c;
        #pragma unroll
        for (int r = 0; r < 4; ++r)
            pbase[(size_t)(rbase + r) * NC + col] = acc1[r];
    }

    // ---- tail: embWeT[h][t] (blocks 0..15), independent of the GEMM ----
    if (blockIdx.x < 16) {
        int idx = blockIdx.x * 256 + tid;        // 0..4095
        int h = idx >> 6, t = idx & 63;
        float s = 0.f;
        #pragma unroll
        for (int e = 0; e < 16; ++e) s += emb[t * 16 + e] * We[e * 64 + h];
        embWeT[idx] = s;
    }
}

// ---------------- Kernel 2: per-row fused head (1 wave = 1 batch row) ---------
__global__ __launch_bounds__(256) void k2_score(
        const float* __restrict__ partials, const float* __restrict__ embWeT,
        const int* __restrict__ action_types, const int* __restrict__ action_counts,
        const int* __restrict__ action,
        const float* __restrict__ b1, const float* __restrict__ bc1,
        const float* __restrict__ W2, const float* __restrict__ b2,
        const float* __restrict__ Wf,
        const float* __restrict__ ba, const float* __restrict__ Wo,
        const float* __restrict__ bo, const float* __restrict__ Wc2,
        const float* __restrict__ bc2, const float* __restrict__ Wc3,
        const float* __restrict__ bc3, float* __restrict__ out) {
    // bf16x2-packed weights: [kp][h] holds (W[2kp][h], W[2kp+1][h])
    __shared__ unsigned sW2p[32][64];
    __shared__ unsigned sWfp[32][64];
    __shared__ unsigned sWc2p[32][64];
    __shared__ unsigned sVTp[32][64];   // (embWeT[2hp][t], embWeT[2hp+1][t])
    __shared__ int scnt[4][64];

    const int tid = threadIdx.x;
    #pragma unroll
    for (int i = 0; i < 8; ++i) {
        int idx = tid + i * 256;        // 0..2047
        int rp = idx >> 6, hh = idx & 63;
        sW2p [rp][hh] = pack_bf16(W2 [(2 * rp) * 64 + hh], W2 [(2 * rp + 1) * 64 + hh]);
        sWfp [rp][hh] = pack_bf16(Wf [(2 * rp) * 64 + hh], Wf [(2 * rp + 1) * 64 + hh]);
        sWc2p[rp][hh] = pack_bf16(Wc2[(2 * rp) * 64 + hh], Wc2[(2 * rp + 1) * 64 + hh]);
        sVTp [rp][hh] = pack_bf16(embWeT[(2 * rp) * 64 + hh], embWeT[(2 * rp + 1) * 64 + hh]);
    }
    scnt[tid >> 6][tid & 63] = 0;
    __syncthreads();

    const int lane = tid & 63;
    const int wid  = tid >> 6;
    const int b    = blockIdx.x * 4 + wid;

    // sum 8 K-split partials, bias, tanh
    const float* pa = partials + (size_t)b * NC + lane;
    float h1v = 0.f, c1v = 0.f;
    #pragma unroll
    for (int s8 = 0; s8 < NSLICE; ++s8) {
        h1v += pa[(size_t)s8 * B_ * NC];
        c1v += pa[(size_t)s8 * B_ * NC + 64];
    }
    h1v = fast_tanh(h1v + b1[lane]);
    c1v = fast_tanh(c1v + bc1[lane]);
    const int* at_row = action_types + (size_t)b * A_;
    const int count = action_counts[b];
    const int base = lane * 8;
    int4 p0 = *reinterpret_cast<const int4*>(at_row + base);
    int4 p1 = *reinterpret_cast<const int4*>(at_row + base + 4);
    const int a_star = action[b];
    const int t_star = at_row[a_star] & 63;

    // feats[h] = tanh(sum_k h1[k]*W2[k][h] + b2[h])
    float f = b2[lane];
    #pragma unroll
    for (int kp = 0; kp < 32; ++kp) {
        unsigned pw = sW2p[kp][lane];
        f += RL(h1v, 2 * kp)     * __uint_as_float(pw << 16);
        f += RL(h1v, 2 * kp + 1) * __uint_as_float(pw & 0xffff0000u);
    }
    f = fast_tanh(f);

    // u[h] = sum_k feats[k]*Wf[k][h] + ba[h]
    float u = ba[lane];
    #pragma unroll
    for (int kp = 0; kp < 32; ++kp) {
        unsigned pw = sWfp[kp][lane];
        u += RL(f, 2 * kp)     * __uint_as_float(pw << 16);
        u += RL(f, 2 * kp + 1) * __uint_as_float(pw & 0xffff0000u);
    }

    // critic: cc = tanh(c1@Wc2+bc2); value = cc.Wc3 + bc3
    float cc = bc2[lane];
    #pragma unroll
    for (int kp = 0; kp < 32; ++kp) {
        unsigned pw = sWc2p[kp][lane];
        cc += RL(c1v, 2 * kp)     * __uint_as_float(pw << 16);
        cc += RL(c1v, 2 * kp + 1) * __uint_as_float(pw & 0xffff0000u);
    }
    cc = fast_tanh(cc);
    float pv = cc * Wc3[lane];
    #pragma unroll
    for (int off = 32; off > 0; off >>= 1) pv += __shfl_xor(pv, off);
    const float value = pv + bc3[0];

    // score-per-type: lane = t
    float s = bo[0];
    #pragma unroll
    for (int hp = 0; hp < 32; ++hp) {
        unsigned pvv = sVTp[hp][lane];
        s += fast_tanh(RL(u, 2 * hp)     + __uint_as_float(pvv << 16))         * Wo[2 * hp];
        s += fast_tanh(RL(u, 2 * hp + 1) + __uint_as_float(pvv & 0xffff0000u)) * Wo[2 * hp + 1];
    }

    // histogram of valid action types (wave-private)
    int* cptr = scnt[wid];
    if (base + 0 < count) atomicAdd(&cptr[p0.x & 63], 1);
    if (base + 1 < count) atomicAdd(&cptr[p0.y & 63], 1);
    if (base + 2 < count) atomicAdd(&cptr[p0.z & 63], 1);
    if (base + 3 < count) atomicAdd(&cptr[p0.w & 63], 1);
    if (base + 4 < count) atomicAdd(&cptr[p1.x & 63], 1);
    if (base + 5 < count) atomicAdd(&cptr[p1.y & 63], 1);
    if (base + 6 < count) atomicAdd(&cptr[p1.z & 63], 1);
    if (base + 7 < count) atomicAdd(&cptr[p1.w & 63], 1);

    // softmax stats over 64 types weighted by counts
    const int cv = cptr[lane];
    float mval = (cv > 0) ? s : -3.0e38f;
    #pragma unroll
    for (int off = 32; off > 0; off >>= 1) mval = fmaxf(mval, __shfl_xor(mval, off));
    const float e  = (float)cv * __expf(s - mval);
    float se = e, sd = e * s;
    #pragma unroll
    for (int off = 32; off > 0; off >>= 1) {
        se += __shfl_xor(se, off);
        sd += __shfl_xor(sd, off);
    }
    const float logZ    = mval + __logf(se);
    const float entropy = logZ - sd / se;
    const float logp    = __shfl(s, t_star) - logZ;

    if (lane == 0) {
        out[b * 3 + 0] = logp;
        out[b * 3 + 1] = entropy;
        out[b * 3 + 2] = value;
    }
}

extern "C" void kernel_launch(void* const* d_in, const int* in_sizes, int n_in,
                              void* d_out, int out_size, void* d_ws, size_t ws_size,
                              hipStream_t stream) {
    const float* x             = (const float*)d_in[0];
    const int*   action_types  = (const int*)  d_in[1];
    const int*   action_counts = (const int*)  d_in[2];
    const int*   action        = (const int*)  d_in[3];
    const float* emb           = (const float*)d_in[4];
    const float* W1            = (const float*)d_in[5];
    const float* b1            = (const float*)d_in[6];
    const float* W2            = (const float*)d_in[7];
    const float* b2            = (const float*)d_in[8];
    const float* Wf            = (const float*)d_in[9];
    const float* We            = (const float*)d_in[10];
    const float* ba            = (const float*)d_in[11];
    const float* Wo            = (const float*)d_in[12];
    const float* bo            = (const float*)d_in[13];
    const float* Wc1           = (const float*)d_in[14];
    const float* bc1           = (const float*)d_in[15];
    const float* Wc2           = (const float*)d_in[16];
    const float* bc2           = (const float*)d_in[17];
    const float* Wc3           = (const float*)d_in[18];
    const float* bc3           = (const float*)d_in[19];
    float* out = (float*)d_out;

    unsigned char* ws = (unsigned char*)d_ws;
    float* embWeT   = (float*)ws;                  // 16 KB
    float* partials = (float*)(ws + 16384);        // 8 MB (8 x 2048 x 128 f32)

    k1_mfma<<<1024, 256, 0, stream>>>(x, W1, Wc1, emb, We, partials, embWeT);
    k2_score<<<512, 256, 0, stream>>>(partials, embWeT, action_types, action_counts,
                                      action, b1, bc1, W2, b2, Wf, ba, Wo, bo,
                                      Wc2, bc2, Wc3, bc3, out);
}

// Round 10
// 26.708 us; speedup vs baseline: 11.5319x; 1.0497x over previous
//
#include <hip/hip_runtime.h>
#include <hip/hip_bf16.h>

#define B_    2048
#define OBS_  1024
#define A_    512
#define NC    128      // [actor 64 | critic 64] hidden cols
#define NSLICE 8       // K-split
#define PADK  136      // halfwords per wT row (128 + 8 pad)

typedef __attribute__((ext_vector_type(8))) short bf16x8;
typedef __attribute__((ext_vector_type(4))) float f32x4;

__device__ __forceinline__ float fast_tanh(float x) {
    return 1.0f - 2.0f / (__expf(2.0f * x) + 1.0f);
}

__device__ __forceinline__ unsigned short rne_bf16(float f) {
    union { float f; unsigned u; } v; v.f = f;
    unsigned u = v.u;
    return (unsigned short)((u + 0x7FFFu + ((u >> 16) & 1u)) >> 16);
}

__device__ __forceinline__ unsigned pack_bf16(float lo, float hi) {
    return (unsigned)rne_bf16(lo) | ((unsigned)rne_bf16(hi) << 16);
}

__device__ __forceinline__ short to_bf16(float f) {
    __hip_bfloat16 h = __float2bfloat16(f);   // RNE
    return *reinterpret_cast<short*>(&h);
}

// broadcast register value from lane k (compile-time k) via SGPR, no LDS
#define RL(x, k) __int_as_float(__builtin_amdgcn_readlane(__float_as_int(x), (k)))

// ws layout (bytes): vTp 8K | W2p 8K | Wfp 8K | Wc2p 8K | partials 8MB
#define WS_VTP   0
#define WS_W2P   8192
#define WS_WFP   16384
#define WS_WC2P  24576
#define WS_PART  32768

// ---------------- Kernel 1: self-contained MFMA GEMM, 8-way K-split -----------
// grid 512: mb = bid>>3 (32-row tile), kslice = bid&7 (128 K each)
// Stage W-slice fp32->bf16 into transposed LDS wT[n][kk]; each ds_read_b128
// B-fragment feeds 2 row-tiles (4 MFMAs). Blocks 0..31 also pre-pack the
// bf16x2 weight tables consumed by k2.
__global__ __launch_bounds__(256) void k1_mfma(
        const float* __restrict__ x, const float* __restrict__ W1,
        const float* __restrict__ Wc1, const float* __restrict__ emb,
        const float* __restrict__ We, const float* __restrict__ W2,
        const float* __restrict__ Wf, const float* __restrict__ Wc2,
        unsigned char* __restrict__ ws) {
    __shared__ unsigned short wT[128 * PADK];   // 34.8 KB
    const int tid    = threadIdx.x;
    const int bid    = blockIdx.x;
    const int mb     = bid >> 3;                // 0..63 -> rows mb*32
    const int kslice = bid & 7;
    const int k0     = kslice * 128;

    // ---- stage W[k0..k0+128)[0..128) -> wT[n][kk] bf16 ----
    {
        const int n  = tid & 127;
        const int th = tid >> 7;                 // 0..1
        const float* src = (n < 64) ? (W1 + n) : (Wc1 + (n - 64));
        #pragma unroll
        for (int gg = 0; gg < 16; ++gg) {
            int kq = gg * 2 + th;                // 0..31
            int k  = k0 + kq * 4;
            float w0 = src[(size_t)(k + 0) * 64];
            float w1 = src[(size_t)(k + 1) * 64];
            float w2 = src[(size_t)(k + 2) * 64];
            float w3 = src[(size_t)(k + 3) * 64];
            unsigned long long v = (unsigned long long)pack_bf16(w0, w1)
                                 | ((unsigned long long)pack_bf16(w2, w3) << 32);
            *reinterpret_cast<unsigned long long*>(&wT[n * PADK + kq * 4]) = v;
        }
    }
    __syncthreads();

    // ---- MFMA: 4 K-iters, 2 ntiles x 2 row-tiles per wave ----
    const int w = tid >> 6;
    const int l = tid & 63;
    const int c = l & 15;
    const int g = l >> 4;

    const float* xrow0 = x + (size_t)(mb * 32 + c) * OBS_ + k0 + g * 8;
    const float* xrow1 = xrow0 + (size_t)16 * OBS_;
    const int nt0 = 2 * w, nt1 = 2 * w + 1;
    const unsigned short* bp0 = &wT[(nt0 * 16 + c) * PADK + g * 8];
    const unsigned short* bp1 = &wT[(nt1 * 16 + c) * PADK + g * 8];

    f32x4 acc00 = {0.f, 0.f, 0.f, 0.f};
    f32x4 acc01 = {0.f, 0.f, 0.f, 0.f};
    f32x4 acc10 = {0.f, 0.f, 0.f, 0.f};
    f32x4 acc11 = {0.f, 0.f, 0.f, 0.f};
    #pragma unroll
    for (int ks = 0; ks < 4; ++ks) {
        const float4* xp0 = (const float4*)(xrow0 + ks * 32);
        const float4* xp1 = (const float4*)(xrow1 + ks * 32);
        float4 a0 = xp0[0], a1 = xp0[1];
        float4 b0 = xp1[0], b1 = xp1[1];
        bf16x8 av0, av1;
        av0[0] = to_bf16(a0.x); av0[1] = to_bf16(a0.y);
        av0[2] = to_bf16(a0.z); av0[3] = to_bf16(a0.w);
        av0[4] = to_bf16(a1.x); av0[5] = to_bf16(a1.y);
        av0[6] = to_bf16(a1.z); av0[7] = to_bf16(a1.w);
        av1[0] = to_bf16(b0.x); av1[1] = to_bf16(b0.y);
        av1[2] = to_bf16(b0.z); av1[3] = to_bf16(b0.w);
        av1[4] = to_bf16(b1.x); av1[5] = to_bf16(b1.y);
        av1[6] = to_bf16(b1.z); av1[7] = to_bf16(b1.w);
        bf16x8 bv0 = *(const bf16x8*)(bp0 + ks * 32);
        bf16x8 bv1 = *(const bf16x8*)(bp1 + ks * 32);
        acc00 = __builtin_amdgcn_mfma_f32_16x16x32_bf16(av0, bv0, acc00, 0, 0, 0);
        acc01 = __builtin_amdgcn_mfma_f32_16x16x32_bf16(av0, bv1, acc01, 0, 0, 0);
        acc10 = __builtin_amdgcn_mfma_f32_16x16x32_bf16(av1, bv0, acc10, 0, 0, 0);
        acc11 = __builtin_amdgcn_mfma_f32_16x16x32_bf16(av1, bv1, acc11, 0, 0, 0);
    }

    // C/D layout: col = lane&15, row = (lane>>4)*4 + reg
    float* pbase = (float*)(ws + WS_PART) + (size_t)kslice * B_ * NC;
    const int col0 = nt0 * 16 + c;
    const int col1 = nt1 * 16 + c;
    const int r0   = mb * 32 + g * 4;
    const int r1   = r0 + 16;
    #pragma unroll
    for (int r = 0; r < 4; ++r) {
        pbase[(size_t)(r0 + r) * NC + col0] = acc00[r];
        pbase[(size_t)(r0 + r) * NC + col1] = acc01[r];
        pbase[(size_t)(r1 + r) * NC + col0] = acc10[r];
        pbase[(size_t)(r1 + r) * NC + col1] = acc11[r];
    }

    // ---- tail: pre-pack k2 weight tables (blocks 0..31) ----
    if (bid < 32) {
        const int job = bid >> 3;               // 0:vTp 1:W2p 2:Wfp 3:Wc2p
        const int idx = (bid & 7) * 256 + tid;  // 0..2047
        if (job == 0) {
            int hp = idx >> 6, t = idx & 63;
            float s0 = 0.f, s1 = 0.f;
            #pragma unroll
            for (int e = 0; e < 16; ++e) {
                float ev = emb[t * 16 + e];
                s0 += ev * We[e * 64 + 2 * hp];
                s1 += ev * We[e * 64 + 2 * hp + 1];
            }
            ((unsigned*)(ws + WS_VTP))[idx] = pack_bf16(s0, s1);
        } else {
            const float* src = (job == 1) ? W2 : (job == 2) ? Wf : Wc2;
            unsigned* dst = (unsigned*)(ws + ((job == 1) ? WS_W2P : (job == 2) ? WS_WFP : WS_WC2P));
            int rp = idx >> 6, hh = idx & 63;
            dst[idx] = pack_bf16(src[(2 * rp) * 64 + hh], src[(2 * rp + 1) * 64 + hh]);
        }
    }
}

// ---------------- Kernel 2: per-row fused head (1 wave = 1 batch row) ---------
__global__ __launch_bounds__(256) void k2_score(
        const unsigned char* __restrict__ ws,
        const int* __restrict__ action_types, const int* __restrict__ action_counts,
        const int* __restrict__ action,
        const float* __restrict__ b1, const float* __restrict__ bc1,
        const float* __restrict__ b2, const float* __restrict__ ba,
        const float* __restrict__ Wo, const float* __restrict__ bo,
        const float* __restrict__ bc2, const float* __restrict__ Wc3,
        const float* __restrict__ bc3, float* __restrict__ out) {
    __shared__ unsigned sW2p[32][64];
    __shared__ unsigned sWfp[32][64];
    __shared__ unsigned sWc2p[32][64];
    __shared__ unsigned sVTp[32][64];
    __shared__ int scnt[4][64];

    const int tid = threadIdx.x;
    {
        const unsigned* gV = (const unsigned*)(ws + WS_VTP);
        const unsigned* g2 = (const unsigned*)(ws + WS_W2P);
        const unsigned* gF = (const unsigned*)(ws + WS_WFP);
        const unsigned* gC = (const unsigned*)(ws + WS_WC2P);
        #pragma unroll
        for (int i = 0; i < 8; ++i) {
            int idx = tid + i * 256;
            ((unsigned*)sVTp)[idx]  = gV[idx];
            ((unsigned*)sW2p)[idx]  = g2[idx];
            ((unsigned*)sWfp)[idx]  = gF[idx];
            ((unsigned*)sWc2p)[idx] = gC[idx];
        }
    }
    scnt[tid >> 6][tid & 63] = 0;
    __syncthreads();

    const int lane = tid & 63;
    const int wid  = tid >> 6;
    const int b    = blockIdx.x * 4 + wid;

    // sum 8 K-split partials, bias, tanh
    const float* pa = (const float*)(ws + WS_PART) + (size_t)b * NC + lane;
    float h1v = 0.f, c1v = 0.f;
    #pragma unroll
    for (int s8 = 0; s8 < NSLICE; ++s8) {
        h1v += pa[(size_t)s8 * B_ * NC];
        c1v += pa[(size_t)s8 * B_ * NC + 64];
    }
    h1v = fast_tanh(h1v + b1[lane]);
    c1v = fast_tanh(c1v + bc1[lane]);
    const int* at_row = action_types + (size_t)b * A_;
    const int count = action_counts[b];
    const int base = lane * 8;
    int4 p0 = *reinterpret_cast<const int4*>(at_row + base);
    int4 p1 = *reinterpret_cast<const int4*>(at_row + base + 4);
    const int a_star = action[b];
    const int t_star = at_row[a_star] & 63;

    // feats[h] = tanh(sum_k h1[k]*W2[k][h] + b2[h])
    float f = b2[lane];
    #pragma unroll
    for (int kp = 0; kp < 32; ++kp) {
        unsigned pw = sW2p[kp][lane];
        f += RL(h1v, 2 * kp)     * __uint_as_float(pw << 16);
        f += RL(h1v, 2 * kp + 1) * __uint_as_float(pw & 0xffff0000u);
    }
    f = fast_tanh(f);

    // u[h] = sum_k feats[k]*Wf[k][h] + ba[h]
    float u = ba[lane];
    #pragma unroll
    for (int kp = 0; kp < 32; ++kp) {
        unsigned pw = sWfp[kp][lane];
        u += RL(f, 2 * kp)     * __uint_as_float(pw << 16);
        u += RL(f, 2 * kp + 1) * __uint_as_float(pw & 0xffff0000u);
    }

    // critic: cc = tanh(c1@Wc2+bc2); value = cc.Wc3 + bc3
    float cc = bc2[lane];
    #pragma unroll
    for (int kp = 0; kp < 32; ++kp) {
        unsigned pw = sWc2p[kp][lane];
        cc += RL(c1v, 2 * kp)     * __uint_as_float(pw << 16);
        cc += RL(c1v, 2 * kp + 1) * __uint_as_float(pw & 0xffff0000u);
    }
    cc = fast_tanh(cc);
    float pv = cc * Wc3[lane];
    #pragma unroll
    for (int off = 32; off > 0; off >>= 1) pv += __shfl_xor(pv, off);
    const float value = pv + bc3[0];

    // score-per-type: lane = t
    float s = bo[0];
    #pragma unroll
    for (int hp = 0; hp < 32; ++hp) {
        unsigned pvv = sVTp[hp][lane];
        s += fast_tanh(RL(u, 2 * hp)     + __uint_as_float(pvv << 16))         * Wo[2 * hp];
        s += fast_tanh(RL(u, 2 * hp + 1) + __uint_as_float(pvv & 0xffff0000u)) * Wo[2 * hp + 1];
    }

    // histogram of valid action types (wave-private)
    int* cptr = scnt[wid];
    if (base + 0 < count) atomicAdd(&cptr[p0.x & 63], 1);
    if (base + 1 < count) atomicAdd(&cptr[p0.y & 63], 1);
    if (base + 2 < count) atomicAdd(&cptr[p0.z & 63], 1);
    if (base + 3 < count) atomicAdd(&cptr[p0.w & 63], 1);
    if (base + 4 < count) atomicAdd(&cptr[p1.x & 63], 1);
    if (base + 5 < count) atomicAdd(&cptr[p1.y & 63], 1);
    if (base + 6 < count) atomicAdd(&cptr[p1.z & 63], 1);
    if (base + 7 < count) atomicAdd(&cptr[p1.w & 63], 1);

    // softmax stats over 64 types weighted by counts
    const int cv = cptr[lane];
    float mval = (cv > 0) ? s : -3.0e38f;
    #pragma unroll
    for (int off = 32; off > 0; off >>= 1) mval = fmaxf(mval, __shfl_xor(mval, off));
    const float e  = (float)cv * __expf(s - mval);
    float se = e, sd = e * s;
    #pragma unroll
    for (int off = 32; off > 0; off >>= 1) {
        se += __shfl_xor(se, off);
        sd += __shfl_xor(sd, off);
    }
    const float logZ    = mval + __logf(se);
    const float entropy = logZ - sd / se;
    const float logp    = __shfl(s, t_star) - logZ;

    if (lane == 0) {
        out[b * 3 + 0] = logp;
        out[b * 3 + 1] = entropy;
        out[b * 3 + 2] = value;
    }
}

extern "C" void kernel_launch(void* const* d_in, const int* in_sizes, int n_in,
                              void* d_out, int out_size, void* d_ws, size_t ws_size,
                              hipStream_t stream) {
    const float* x             = (const float*)d_in[0];
    const int*   action_types  = (const int*)  d_in[1];
    const int*   action_counts = (const int*)  d_in[2];
    const int*   action        = (const int*)  d_in[3];
    const float* emb           = (const float*)d_in[4];
    const float* W1            = (const float*)d_in[5];
    const float* b1            = (const float*)d_in[6];
    const float* W2            = (const float*)d_in[7];
    const float* b2            = (const float*)d_in[8];
    const float* Wf            = (const float*)d_in[9];
    const float* We            = (const float*)d_in[10];
    const float* ba            = (const float*)d_in[11];
    const float* Wo            = (const float*)d_in[12];
    const float* bo            = (const float*)d_in[13];
    const float* Wc1           = (const float*)d_in[14];
    const float* bc1           = (const float*)d_in[15];
    const float* Wc2           = (const float*)d_in[16];
    const float* bc2           = (const float*)d_in[17];
    const float* Wc3           = (const float*)d_in[18];
    const float* bc3           = (const float*)d_in[19];
    float* out = (float*)d_out;
    unsigned char* ws = (unsigned char*)d_ws;

    k1_mfma<<<512, 256, 0, stream>>>(x, W1, Wc1, emb, We, W2, Wf, Wc2, ws);
    k2_score<<<512, 256, 0, stream>>>(ws, action_types, action_counts, action,
                                      b1, bc1, b2, ba, Wo, bo, bc2, Wc3, bc3, out);
}

// Round 11
// 24.679 us; speedup vs baseline: 12.4798x; 1.0822x over previous
//
#include <hip/hip_runtime.h>
#include <hip/hip_bf16.h>

#define B_    2048
#define OBS_  1024
#define A_    512
#define NC    128      // [actor 64 | critic 64] hidden cols
#define NSLICE 8       // K-split
#define PADK  136      // halfwords per wT row (128 + 8 pad)

typedef __attribute__((ext_vector_type(8))) short bf16x8;
typedef __attribute__((ext_vector_type(4))) float f32x4;

__device__ __forceinline__ float fast_tanh(float x) {
    return 1.0f - 2.0f / (__expf(2.0f * x) + 1.0f);
}

__device__ __forceinline__ unsigned short rne_bf16(float f) {
    union { float f; unsigned u; } v; v.f = f;
    unsigned u = v.u;
    return (unsigned short)((u + 0x7FFFu + ((u >> 16) & 1u)) >> 16);
}

__device__ __forceinline__ unsigned pack_bf16(float lo, float hi) {
    return (unsigned)rne_bf16(lo) | ((unsigned)rne_bf16(hi) << 16);
}

__device__ __forceinline__ short to_bf16(float f) {
    __hip_bfloat16 h = __float2bfloat16(f);   // RNE
    return *reinterpret_cast<short*>(&h);
}

__device__ __forceinline__ float bf16_lo(unsigned p) { return __uint_as_float(p << 16); }
__device__ __forceinline__ float bf16_hi(unsigned p) { return __uint_as_float(p & 0xffff0000u); }
__device__ __forceinline__ float bf16_f(unsigned short v) { return __uint_as_float(((unsigned)v) << 16); }

// broadcast register value from lane k (compile-time k) via SGPR, no LDS
#define RL(x, k) __int_as_float(__builtin_amdgcn_readlane(__float_as_int(x), (k)))

// ws layout (bytes): vTp 8K | W2p 8K | Wfp 8K | Wc2p 8K | partials 4MB (bf16)
#define WS_VTP   0
#define WS_W2P   8192
#define WS_WFP   16384
#define WS_WC2P  24576
#define WS_PART  32768

// ---------------- Kernel 1: self-contained MFMA GEMM, 8-way K-split -----------
// grid 512: mb = bid>>3 (32-row tile), kslice = bid&7 (128 K each)
// Stage W-slice fp32->bf16 into transposed LDS wT[n][kk]; each ds_read_b128
// B-fragment feeds 2 row-tiles (4 MFMAs). Partials stored bf16 [row][ks][col].
// Blocks 0..31 also pre-pack the bf16x2 weight tables consumed by k2.
__global__ __launch_bounds__(256) void k1_mfma(
        const float* __restrict__ x, const float* __restrict__ W1,
        const float* __restrict__ Wc1, const float* __restrict__ emb,
        const float* __restrict__ We, const float* __restrict__ W2,
        const float* __restrict__ Wf, const float* __restrict__ Wc2,
        unsigned char* __restrict__ ws) {
    __shared__ unsigned short wT[128 * PADK];   // 34.8 KB
    const int tid    = threadIdx.x;
    const int bid    = blockIdx.x;
    const int mb     = bid >> 3;                // 0..63 -> rows mb*32
    const int kslice = bid & 7;
    const int k0     = kslice * 128;

    // ---- stage W[k0..k0+128)[0..128) -> wT[n][kk] bf16 ----
    {
        const int n  = tid & 127;
        const int th = tid >> 7;                 // 0..1
        const float* src = (n < 64) ? (W1 + n) : (Wc1 + (n - 64));
        #pragma unroll
        for (int gg = 0; gg < 16; ++gg) {
            int kq = gg * 2 + th;                // 0..31
            int k  = k0 + kq * 4;
            float w0 = src[(size_t)(k + 0) * 64];
            float w1 = src[(size_t)(k + 1) * 64];
            float w2 = src[(size_t)(k + 2) * 64];
            float w3 = src[(size_t)(k + 3) * 64];
            unsigned long long v = (unsigned long long)pack_bf16(w0, w1)
                                 | ((unsigned long long)pack_bf16(w2, w3) << 32);
            *reinterpret_cast<unsigned long long*>(&wT[n * PADK + kq * 4]) = v;
        }
    }
    __syncthreads();

    // ---- MFMA: 4 K-iters, 2 ntiles x 2 row-tiles per wave ----
    const int w = tid >> 6;
    const int l = tid & 63;
    const int c = l & 15;
    const int g = l >> 4;

    const float* xrow0 = x + (size_t)(mb * 32 + c) * OBS_ + k0 + g * 8;
    const float* xrow1 = xrow0 + (size_t)16 * OBS_;
    const int nt0 = 2 * w, nt1 = 2 * w + 1;
    const unsigned short* bp0 = &wT[(nt0 * 16 + c) * PADK + g * 8];
    const unsigned short* bp1 = &wT[(nt1 * 16 + c) * PADK + g * 8];

    f32x4 acc00 = {0.f, 0.f, 0.f, 0.f};
    f32x4 acc01 = {0.f, 0.f, 0.f, 0.f};
    f32x4 acc10 = {0.f, 0.f, 0.f, 0.f};
    f32x4 acc11 = {0.f, 0.f, 0.f, 0.f};
    #pragma unroll
    for (int ks = 0; ks < 4; ++ks) {
        const float4* xp0 = (const float4*)(xrow0 + ks * 32);
        const float4* xp1 = (const float4*)(xrow1 + ks * 32);
        float4 a0 = xp0[0], a1 = xp0[1];
        float4 b0 = xp1[0], b1 = xp1[1];
        bf16x8 av0, av1;
        av0[0] = to_bf16(a0.x); av0[1] = to_bf16(a0.y);
        av0[2] = to_bf16(a0.z); av0[3] = to_bf16(a0.w);
        av0[4] = to_bf16(a1.x); av0[5] = to_bf16(a1.y);
        av0[6] = to_bf16(a1.z); av0[7] = to_bf16(a1.w);
        av1[0] = to_bf16(b0.x); av1[1] = to_bf16(b0.y);
        av1[2] = to_bf16(b0.z); av1[3] = to_bf16(b0.w);
        av1[4] = to_bf16(b1.x); av1[5] = to_bf16(b1.y);
        av1[6] = to_bf16(b1.z); av1[7] = to_bf16(b1.w);
        bf16x8 bv0 = *(const bf16x8*)(bp0 + ks * 32);
        bf16x8 bv1 = *(const bf16x8*)(bp1 + ks * 32);
        acc00 = __builtin_amdgcn_mfma_f32_16x16x32_bf16(av0, bv0, acc00, 0, 0, 0);
        acc01 = __builtin_amdgcn_mfma_f32_16x16x32_bf16(av0, bv1, acc01, 0, 0, 0);
        acc10 = __builtin_amdgcn_mfma_f32_16x16x32_bf16(av1, bv0, acc10, 0, 0, 0);
        acc11 = __builtin_amdgcn_mfma_f32_16x16x32_bf16(av1, bv1, acc11, 0, 0, 0);
    }

    // C/D layout: col = lane&15, row = (lane>>4)*4 + reg
    // partials bf16 [row][kslice][col]
    unsigned short* pbase = (unsigned short*)(ws + WS_PART);
    const int col0 = nt0 * 16 + c;
    const int col1 = nt1 * 16 + c;
    const int r0   = mb * 32 + g * 4;
    const int r1   = r0 + 16;
    #pragma unroll
    for (int r = 0; r < 4; ++r) {
        pbase[((size_t)(r0 + r) * NSLICE + kslice) * NC + col0] = (unsigned short)to_bf16(acc00[r]);
        pbase[((size_t)(r0 + r) * NSLICE + kslice) * NC + col1] = (unsigned short)to_bf16(acc01[r]);
        pbase[((size_t)(r1 + r) * NSLICE + kslice) * NC + col0] = (unsigned short)to_bf16(acc10[r]);
        pbase[((size_t)(r1 + r) * NSLICE + kslice) * NC + col1] = (unsigned short)to_bf16(acc11[r]);
    }

    // ---- tail: pre-pack k2 weight tables (blocks 0..31) ----
    if (bid < 32) {
        const int job = bid >> 3;               // 0:vTp 1:W2p 2:Wfp 3:Wc2p
        const int idx = (bid & 7) * 256 + tid;  // 0..2047
        if (job == 0) {
            int hp = idx >> 6, t = idx & 63;
            float s0 = 0.f, s1 = 0.f;
            #pragma unroll
            for (int e = 0; e < 16; ++e) {
                float ev = emb[t * 16 + e];
                s0 += ev * We[e * 64 + 2 * hp];
                s1 += ev * We[e * 64 + 2 * hp + 1];
            }
            ((unsigned*)(ws + WS_VTP))[idx] = pack_bf16(s0, s1);
        } else {
            const float* src = (job == 1) ? W2 : (job == 2) ? Wf : Wc2;
            unsigned* dst = (unsigned*)(ws + ((job == 1) ? WS_W2P : (job == 2) ? WS_WFP : WS_WC2P));
            int rp = idx >> 6, hh = idx & 63;
            dst[idx] = pack_bf16(src[(2 * rp) * 64 + hh], src[(2 * rp + 1) * 64 + hh]);
        }
    }
}

// ---------------- Kernel 2: per-row fused head (1 wave = 1 batch row) ---------
__global__ __launch_bounds__(256) void k2_score(
        const unsigned char* __restrict__ ws,
        const int* __restrict__ action_types, const int* __restrict__ action_counts,
        const int* __restrict__ action,
        const float* __restrict__ b1, const float* __restrict__ bc1,
        const float* __restrict__ b2, const float* __restrict__ ba,
        const float* __restrict__ Wo, const float* __restrict__ bo,
        const float* __restrict__ bc2, const float* __restrict__ Wc3,
        const float* __restrict__ bc3, float* __restrict__ out) {
    __shared__ unsigned sW2p[32][64];
    __shared__ unsigned sWfp[32][64];
    __shared__ unsigned sWc2p[32][64];
    __shared__ unsigned sVTp[32][64];
    __shared__ int scnt[4][64];

    const int tid = threadIdx.x;
    {
        const unsigned* gV = (const unsigned*)(ws + WS_VTP);
        const unsigned* g2 = (const unsigned*)(ws + WS_W2P);
        const unsigned* gF = (const unsigned*)(ws + WS_WFP);
        const unsigned* gC = (const unsigned*)(ws + WS_WC2P);
        #pragma unroll
        for (int i = 0; i < 8; ++i) {
            int idx = tid + i * 256;
            ((unsigned*)sVTp)[idx]  = gV[idx];
            ((unsigned*)sW2p)[idx]  = g2[idx];
            ((unsigned*)sWfp)[idx]  = gF[idx];
            ((unsigned*)sWc2p)[idx] = gC[idx];
        }
    }
    scnt[tid >> 6][tid & 63] = 0;
    __syncthreads();

    const int lane = tid & 63;
    const int wid  = tid >> 6;
    const int b    = blockIdx.x * 4 + wid;

    // sum 8 bf16 K-split partials [row][ks][col], bias, tanh (2-way ILP)
    const unsigned short* pa = (const unsigned short*)(ws + WS_PART)
                             + (size_t)b * NSLICE * NC + lane;
    float h1a = 0.f, h1b = 0.f, c1a = 0.f, c1b = 0.f;
    #pragma unroll
    for (int s8 = 0; s8 < NSLICE; s8 += 2) {
        h1a += bf16_f(pa[s8 * NC]);
        h1b += bf16_f(pa[(s8 + 1) * NC]);
        c1a += bf16_f(pa[s8 * NC + 64]);
        c1b += bf16_f(pa[(s8 + 1) * NC + 64]);
    }
    float h1v = fast_tanh(h1a + h1b + b1[lane]);
    float c1v = fast_tanh(c1a + c1b + bc1[lane]);

    const int* at_row = action_types + (size_t)b * A_;
    const int count = action_counts[b];
    const int base = lane * 8;
    int4 p0 = *reinterpret_cast<const int4*>(at_row + base);
    int4 p1 = *reinterpret_cast<const int4*>(at_row + base + 4);
    const int a_star = action[b];
    const int t_star = at_row[a_star] & 63;

    // feats[h] = tanh(sum_k h1[k]*W2[k][h] + b2[h])  (4 accumulator chains)
    float f0 = b2[lane], f1 = 0.f, f2 = 0.f, f3 = 0.f;
    #pragma unroll
    for (int kp = 0; kp < 32; kp += 2) {
        unsigned pwA = sW2p[kp][lane];
        unsigned pwB = sW2p[kp + 1][lane];
        f0 += RL(h1v, 2 * kp)     * bf16_lo(pwA);
        f1 += RL(h1v, 2 * kp + 1) * bf16_hi(pwA);
        f2 += RL(h1v, 2 * kp + 2) * bf16_lo(pwB);
        f3 += RL(h1v, 2 * kp + 3) * bf16_hi(pwB);
    }
    const float f = fast_tanh((f0 + f1) + (f2 + f3));

    // u[h] = sum_k feats[k]*Wf[k][h] + ba[h]
    float u0 = ba[lane], u1 = 0.f, u2 = 0.f, u3 = 0.f;
    #pragma unroll
    for (int kp = 0; kp < 32; kp += 2) {
        unsigned pwA = sWfp[kp][lane];
        unsigned pwB = sWfp[kp + 1][lane];
        u0 += RL(f, 2 * kp)     * bf16_lo(pwA);
        u1 += RL(f, 2 * kp + 1) * bf16_hi(pwA);
        u2 += RL(f, 2 * kp + 2) * bf16_lo(pwB);
        u3 += RL(f, 2 * kp + 3) * bf16_hi(pwB);
    }
    const float u = (u0 + u1) + (u2 + u3);

    // critic: cc = tanh(c1@Wc2+bc2); value = cc.Wc3 + bc3
    float g0 = bc2[lane], g1 = 0.f, g2 = 0.f, g3 = 0.f;
    #pragma unroll
    for (int kp = 0; kp < 32; kp += 2) {
        unsigned pwA = sWc2p[kp][lane];
        unsigned pwB = sWc2p[kp + 1][lane];
        g0 += RL(c1v, 2 * kp)     * bf16_lo(pwA);
        g1 += RL(c1v, 2 * kp + 1) * bf16_hi(pwA);
        g2 += RL(c1v, 2 * kp + 2) * bf16_lo(pwB);
        g3 += RL(c1v, 2 * kp + 3) * bf16_hi(pwB);
    }
    float cc = fast_tanh((g0 + g1) + (g2 + g3));
    float pv = cc * Wc3[lane];
    #pragma unroll
    for (int off = 32; off > 0; off >>= 1) pv += __shfl_xor(pv, off);
    const float value = pv + bc3[0];

    // score-per-type: lane = t  (4 accumulator chains)
    float s0 = bo[0], s1 = 0.f, s2 = 0.f, s3 = 0.f;
    #pragma unroll
    for (int hp = 0; hp < 32; hp += 2) {
        unsigned pvA = sVTp[hp][lane];
        unsigned pvB = sVTp[hp + 1][lane];
        s0 += fast_tanh(RL(u, 2 * hp)     + bf16_lo(pvA)) * Wo[2 * hp];
        s1 += fast_tanh(RL(u, 2 * hp + 1) + bf16_hi(pvA)) * Wo[2 * hp + 1];
        s2 += fast_tanh(RL(u, 2 * hp + 2) + bf16_lo(pvB)) * Wo[2 * hp + 2];
        s3 += fast_tanh(RL(u, 2 * hp + 3) + bf16_hi(pvB)) * Wo[2 * hp + 3];
    }
    const float s = (s0 + s1) + (s2 + s3);

    // histogram of valid action types (wave-private)
    int* cptr = scnt[wid];
    if (base + 0 < count) atomicAdd(&cptr[p0.x & 63], 1);
    if (base + 1 < count) atomicAdd(&cptr[p0.y & 63], 1);
    if (base + 2 < count) atomicAdd(&cptr[p0.z & 63], 1);
    if (base + 3 < count) atomicAdd(&cptr[p0.w & 63], 1);
    if (base + 4 < count) atomicAdd(&cptr[p1.x & 63], 1);
    if (base + 5 < count) atomicAdd(&cptr[p1.y & 63], 1);
    if (base + 6 < count) atomicAdd(&cptr[p1.z & 63], 1);
    if (base + 7 < count) atomicAdd(&cptr[p1.w & 63], 1);

    // softmax stats over 64 types weighted by counts
    const int cv = cptr[lane];
    float mval = (cv > 0) ? s : -3.0e38f;
    #pragma unroll
    for (int off = 32; off > 0; off >>= 1) mval = fmaxf(mval, __shfl_xor(mval, off));
    const float e  = (float)cv * __expf(s - mval);
    float se = e, sd = e * s;
    #pragma unroll
    for (int off = 32; off > 0; off >>= 1) {
        se += __shfl_xor(se, off);
        sd += __shfl_xor(sd, off);
    }
    const float logZ    = mval + __logf(se);
    const float entropy = logZ - sd / se;
    const float logp    = __shfl(s, t_star) - logZ;

    if (lane == 0) {
        out[b * 3 + 0] = logp;
        out[b * 3 + 1] = entropy;
        out[b * 3 + 2] = value;
    }
}

extern "C" void kernel_launch(void* const* d_in, const int* in_sizes, int n_in,
                              void* d_out, int out_size, void* d_ws, size_t ws_size,
                              hipStream_t stream) {
    const float* x             = (const float*)d_in[0];
    const int*   action_types  = (const int*)  d_in[1];
    const int*   action_counts = (const int*)  d_in[2];
    const int*   action        = (const int*)  d_in[3];
    const float* emb           = (const float*)d_in[4];
    const float* W1            = (const float*)d_in[5];
    const float* b1            = (const float*)d_in[6];
    const float* W2            = (const float*)d_in[7];
    const float* b2            = (const float*)d_in[8];
    const float* Wf            = (const float*)d_in[9];
    const float* We            = (const float*)d_in[10];
    const float* ba            = (const float*)d_in[11];
    const float* Wo            = (const float*)d_in[12];
    const float* bo            = (const float*)d_in[13];
    const float* Wc1           = (const float*)d_in[14];
    const float* bc1           = (const float*)d_in[15];
    const float* Wc2           = (const float*)d_in[16];
    const float* bc2           = (const float*)d_in[17];
    const float* Wc3           = (const float*)d_in[18];
    const float* bc3           = (const float*)d_in[19];
    float* out = (float*)d_out;
    unsigned char* ws = (unsigned char*)d_ws;

    k1_mfma<<<512, 256, 0, stream>>>(x, W1, Wc1, emb, We, W2, Wf, Wc2, ws);
    k2_score<<<512, 256, 0, stream>>>(ws, action_types, action_counts, action,
                                      b1, bc1, b2, ba, Wo, bo, bc2, Wc3, bc3, out);
}

// Round 12
// 24.051 us; speedup vs baseline: 12.8055x; 1.0261x over previous
//
#include <hip/hip_runtime.h>
#include <hip/hip_bf16.h>

#define B_    2048
#define OBS_  1024
#define A_    512
#define NC    128      // [actor 64 | critic 64] hidden cols
#define NSLICE 8       // K-split
#define PADK  136      // halfwords per wT row (128 + 8 pad)
#define TWO_LOG2E 2.8853900817779268f

typedef __attribute__((ext_vector_type(8))) short bf16x8;
typedef __attribute__((ext_vector_type(4))) float f32x4;

__device__ __forceinline__ float fast_tanh(float x) {
    return 1.0f - 2.0f / (__expf(2.0f * x) + 1.0f);
}

// tanh where z is PRE-SCALED by 2*log2(e): tanh(x) with z = x*2log2e
__device__ __forceinline__ float tanh_exp2(float z) {
    return 1.0f - 2.0f / (__builtin_amdgcn_exp2f(z) + 1.0f);
}

__device__ __forceinline__ unsigned short rne_bf16(float f) {
    union { float f; unsigned u; } v; v.f = f;
    unsigned u = v.u;
    return (unsigned short)((u + 0x7FFFu + ((u >> 16) & 1u)) >> 16);
}

__device__ __forceinline__ unsigned pack_bf16(float lo, float hi) {
    return (unsigned)rne_bf16(lo) | ((unsigned)rne_bf16(hi) << 16);
}

__device__ __forceinline__ short to_bf16(float f) {
    __hip_bfloat16 h = __float2bfloat16(f);   // RNE
    return *reinterpret_cast<short*>(&h);
}

__device__ __forceinline__ float bf16_lo(unsigned p) { return __uint_as_float(p << 16); }
__device__ __forceinline__ float bf16_hi(unsigned p) { return __uint_as_float(p & 0xffff0000u); }
__device__ __forceinline__ float bf16_f(unsigned short v) { return __uint_as_float(((unsigned)v) << 16); }

// broadcast register value from lane k (compile-time k) via SGPR, no LDS
#define RL(x, k) __int_as_float(__builtin_amdgcn_readlane(__float_as_int(x), (k)))

// ws layout (bytes): vTp 8K | W2p 8K | Wfp 8K | Wc2p 8K | partials 4MB (bf16)
#define WS_VTP   0
#define WS_W2P   8192
#define WS_WFP   16384
#define WS_WC2P  24576
#define WS_PART  32768

// ---------------- Kernel 1: self-contained MFMA GEMM, 8-way K-split -----------
// grid 512: mb = bid>>3 (32-row tile), kslice = bid&7 (128 K each)
// Stage W-slice fp32->bf16 into transposed LDS wT[n][kk]; each ds_read_b128
// B-fragment feeds 2 row-tiles (4 MFMAs). Partials stored bf16 [row][ks][col].
// Blocks 0..31 also pre-pack the bf16x2 weight tables consumed by k2
// (vT table pre-scaled by 2*log2e for k2's exp2-tanh).
__global__ __launch_bounds__(256) void k1_mfma(
        const float* __restrict__ x, const float* __restrict__ W1,
        const float* __restrict__ Wc1, const float* __restrict__ emb,
        const float* __restrict__ We, const float* __restrict__ W2,
        const float* __restrict__ Wf, const float* __restrict__ Wc2,
        unsigned char* __restrict__ ws) {
    __shared__ unsigned short wT[128 * PADK];   // 34.8 KB
    const int tid    = threadIdx.x;
    const int bid    = blockIdx.x;
    const int mb     = bid >> 3;                // 0..63 -> rows mb*32
    const int kslice = bid & 7;
    const int k0     = kslice * 128;

    // ---- stage W[k0..k0+128)[0..128) -> wT[n][kk] bf16 ----
    {
        const int n  = tid & 127;
        const int th = tid >> 7;                 // 0..1
        const float* src = (n < 64) ? (W1 + n) : (Wc1 + (n - 64));
        #pragma unroll
        for (int gg = 0; gg < 16; ++gg) {
            int kq = gg * 2 + th;                // 0..31
            int k  = k0 + kq * 4;
            float w0 = src[(size_t)(k + 0) * 64];
            float w1 = src[(size_t)(k + 1) * 64];
            float w2 = src[(size_t)(k + 2) * 64];
            float w3 = src[(size_t)(k + 3) * 64];
            unsigned long long v = (unsigned long long)pack_bf16(w0, w1)
                                 | ((unsigned long long)pack_bf16(w2, w3) << 32);
            *reinterpret_cast<unsigned long long*>(&wT[n * PADK + kq * 4]) = v;
        }
    }
    __syncthreads();

    // ---- MFMA: 4 K-iters, 2 ntiles x 2 row-tiles per wave ----
    const int w = tid >> 6;
    const int l = tid & 63;
    const int c = l & 15;
    const int g = l >> 4;

    const float* xrow0 = x + (size_t)(mb * 32 + c) * OBS_ + k0 + g * 8;
    const float* xrow1 = xrow0 + (size_t)16 * OBS_;
    const int nt0 = 2 * w, nt1 = 2 * w + 1;
    const unsigned short* bp0 = &wT[(nt0 * 16 + c) * PADK + g * 8];
    const unsigned short* bp1 = &wT[(nt1 * 16 + c) * PADK + g * 8];

    f32x4 acc00 = {0.f, 0.f, 0.f, 0.f};
    f32x4 acc01 = {0.f, 0.f, 0.f, 0.f};
    f32x4 acc10 = {0.f, 0.f, 0.f, 0.f};
    f32x4 acc11 = {0.f, 0.f, 0.f, 0.f};
    #pragma unroll
    for (int ks = 0; ks < 4; ++ks) {
        const float4* xp0 = (const float4*)(xrow0 + ks * 32);
        const float4* xp1 = (const float4*)(xrow1 + ks * 32);
        float4 a0 = xp0[0], a1 = xp0[1];
        float4 b0 = xp1[0], b1 = xp1[1];
        bf16x8 av0, av1;
        av0[0] = to_bf16(a0.x); av0[1] = to_bf16(a0.y);
        av0[2] = to_bf16(a0.z); av0[3] = to_bf16(a0.w);
        av0[4] = to_bf16(a1.x); av0[5] = to_bf16(a1.y);
        av0[6] = to_bf16(a1.z); av0[7] = to_bf16(a1.w);
        av1[0] = to_bf16(b0.x); av1[1] = to_bf16(b0.y);
        av1[2] = to_bf16(b0.z); av1[3] = to_bf16(b0.w);
        av1[4] = to_bf16(b1.x); av1[5] = to_bf16(b1.y);
        av1[6] = to_bf16(b1.z); av1[7] = to_bf16(b1.w);
        bf16x8 bv0 = *(const bf16x8*)(bp0 + ks * 32);
        bf16x8 bv1 = *(const bf16x8*)(bp1 + ks * 32);
        acc00 = __builtin_amdgcn_mfma_f32_16x16x32_bf16(av0, bv0, acc00, 0, 0, 0);
        acc01 = __builtin_amdgcn_mfma_f32_16x16x32_bf16(av0, bv1, acc01, 0, 0, 0);
        acc10 = __builtin_amdgcn_mfma_f32_16x16x32_bf16(av1, bv0, acc10, 0, 0, 0);
        acc11 = __builtin_amdgcn_mfma_f32_16x16x32_bf16(av1, bv1, acc11, 0, 0, 0);
    }

    // C/D layout: col = lane&15, row = (lane>>4)*4 + reg
    // partials bf16 [row][kslice][col]
    unsigned short* pbase = (unsigned short*)(ws + WS_PART);
    const int col0 = nt0 * 16 + c;
    const int col1 = nt1 * 16 + c;
    const int r0   = mb * 32 + g * 4;
    const int r1   = r0 + 16;
    #pragma unroll
    for (int r = 0; r < 4; ++r) {
        pbase[((size_t)(r0 + r) * NSLICE + kslice) * NC + col0] = (unsigned short)to_bf16(acc00[r]);
        pbase[((size_t)(r0 + r) * NSLICE + kslice) * NC + col1] = (unsigned short)to_bf16(acc01[r]);
        pbase[((size_t)(r1 + r) * NSLICE + kslice) * NC + col0] = (unsigned short)to_bf16(acc10[r]);
        pbase[((size_t)(r1 + r) * NSLICE + kslice) * NC + col1] = (unsigned short)to_bf16(acc11[r]);
    }

    // ---- tail: pre-pack k2 weight tables (blocks 0..31) ----
    if (bid < 32) {
        const int job = bid >> 3;               // 0:vTp 1:W2p 2:Wfp 3:Wc2p
        const int idx = (bid & 7) * 256 + tid;  // 0..2047
        if (job == 0) {
            int hp = idx >> 6, t = idx & 63;
            float s0 = 0.f, s1 = 0.f;
            #pragma unroll
            for (int e = 0; e < 16; ++e) {
                float ev = emb[t * 16 + e];
                s0 += ev * We[e * 64 + 2 * hp];
                s1 += ev * We[e * 64 + 2 * hp + 1];
            }
            // pre-scale by 2*log2e for k2's exp2-based tanh
            ((unsigned*)(ws + WS_VTP))[idx] = pack_bf16(s0 * TWO_LOG2E, s1 * TWO_LOG2E);
        } else {
            const float* src = (job == 1) ? W2 : (job == 2) ? Wf : Wc2;
            unsigned* dst = (unsigned*)(ws + ((job == 1) ? WS_W2P : (job == 2) ? WS_WFP : WS_WC2P));
            int rp = idx >> 6, hh = idx & 63;
            dst[idx] = pack_bf16(src[(2 * rp) * 64 + hh], src[(2 * rp + 1) * 64 + hh]);
        }
    }
}

// ---------------- Kernel 2: per-row fused head (1 wave = 1 batch row) ---------
// 256 blocks x 512 threads (8 waves): halves per-block table staging traffic.
__global__ __launch_bounds__(512) void k2_score(
        const unsigned char* __restrict__ ws,
        const int* __restrict__ action_types, const int* __restrict__ action_counts,
        const int* __restrict__ action,
        const float* __restrict__ b1, const float* __restrict__ bc1,
        const float* __restrict__ b2, const float* __restrict__ ba,
        const float* __restrict__ Wo, const float* __restrict__ bo,
        const float* __restrict__ bc2, const float* __restrict__ Wc3,
        const float* __restrict__ bc3, float* __restrict__ out) {
    __shared__ unsigned sW2p[32][64];
    __shared__ unsigned sWfp[32][64];
    __shared__ unsigned sWc2p[32][64];
    __shared__ unsigned sVTp[32][64];
    __shared__ int scnt[8][64];

    const int tid = threadIdx.x;
    {
        const unsigned* gV = (const unsigned*)(ws + WS_VTP);
        const unsigned* g2 = (const unsigned*)(ws + WS_W2P);
        const unsigned* gF = (const unsigned*)(ws + WS_WFP);
        const unsigned* gC = (const unsigned*)(ws + WS_WC2P);
        #pragma unroll
        for (int i = 0; i < 4; ++i) {
            int idx = tid + i * 512;
            ((unsigned*)sVTp)[idx]  = gV[idx];
            ((unsigned*)sW2p)[idx]  = g2[idx];
            ((unsigned*)sWfp)[idx]  = gF[idx];
            ((unsigned*)sWc2p)[idx] = gC[idx];
        }
    }
    scnt[tid >> 6][tid & 63] = 0;
    __syncthreads();

    const int lane = tid & 63;
    const int wid  = tid >> 6;           // 0..7
    const int b    = blockIdx.x * 8 + wid;

    // sum 8 bf16 K-split partials [row][ks][col], bias, tanh (2-way ILP)
    const unsigned short* pa = (const unsigned short*)(ws + WS_PART)
                             + (size_t)b * NSLICE * NC + lane;
    float h1a = 0.f, h1b = 0.f, c1a = 0.f, c1b = 0.f;
    #pragma unroll
    for (int s8 = 0; s8 < NSLICE; s8 += 2) {
        h1a += bf16_f(pa[s8 * NC]);
        h1b += bf16_f(pa[(s8 + 1) * NC]);
        c1a += bf16_f(pa[s8 * NC + 64]);
        c1b += bf16_f(pa[(s8 + 1) * NC + 64]);
    }
    float h1v = fast_tanh(h1a + h1b + b1[lane]);
    float c1v = fast_tanh(c1a + c1b + bc1[lane]);

    const int* at_row = action_types + (size_t)b * A_;
    const int count = action_counts[b];
    const int base = lane * 8;
    int4 p0 = *reinterpret_cast<const int4*>(at_row + base);
    int4 p1 = *reinterpret_cast<const int4*>(at_row + base + 4);
    const int a_star = action[b];
    const int t_star = at_row[a_star] & 63;

    // feats[h] = tanh(sum_k h1[k]*W2[k][h] + b2[h])  (4 accumulator chains)
    float f0 = b2[lane], f1 = 0.f, f2 = 0.f, f3 = 0.f;
    #pragma unroll
    for (int kp = 0; kp < 32; kp += 2) {
        unsigned pwA = sW2p[kp][lane];
        unsigned pwB = sW2p[kp + 1][lane];
        f0 += RL(h1v, 2 * kp)     * bf16_lo(pwA);
        f1 += RL(h1v, 2 * kp + 1) * bf16_hi(pwA);
        f2 += RL(h1v, 2 * kp + 2) * bf16_lo(pwB);
        f3 += RL(h1v, 2 * kp + 3) * bf16_hi(pwB);
    }
    const float f = fast_tanh((f0 + f1) + (f2 + f3));

    // u[h] = sum_k feats[k]*Wf[k][h] + ba[h]
    float u0 = ba[lane], u1 = 0.f, u2 = 0.f, u3 = 0.f;
    #pragma unroll
    for (int kp = 0; kp < 32; kp += 2) {
        unsigned pwA = sWfp[kp][lane];
        unsigned pwB = sWfp[kp + 1][lane];
        u0 += RL(f, 2 * kp)     * bf16_lo(pwA);
        u1 += RL(f, 2 * kp + 1) * bf16_hi(pwA);
        u2 += RL(f, 2 * kp + 2) * bf16_lo(pwB);
        u3 += RL(f, 2 * kp + 3) * bf16_hi(pwB);
    }
    // pre-scale u by 2*log2e so the score loop uses native exp2 tanh
    const float u = ((u0 + u1) + (u2 + u3)) * TWO_LOG2E;

    // critic: cc = tanh(c1@Wc2+bc2); value = cc.Wc3 + bc3
    float g0 = bc2[lane], g1 = 0.f, g2 = 0.f, g3 = 0.f;
    #pragma unroll
    for (int kp = 0; kp < 32; kp += 2) {
        unsigned pwA = sWc2p[kp][lane];
        unsigned pwB = sWc2p[kp + 1][lane];
        g0 += RL(c1v, 2 * kp)     * bf16_lo(pwA);
        g1 += RL(c1v, 2 * kp + 1) * bf16_hi(pwA);
        g2 += RL(c1v, 2 * kp + 2) * bf16_lo(pwB);
        g3 += RL(c1v, 2 * kp + 3) * bf16_hi(pwB);
    }
    float cc = fast_tanh((g0 + g1) + (g2 + g3));
    float pv = cc * Wc3[lane];
    #pragma unroll
    for (int off = 32; off > 0; off >>= 1) pv += __shfl_xor(pv, off);
    const float value = pv + bc3[0];

    // score-per-type: lane = t  (4 accumulator chains; vT pre-scaled)
    float s0 = bo[0], s1 = 0.f, s2 = 0.f, s3 = 0.f;
    #pragma unroll
    for (int hp = 0; hp < 32; hp += 2) {
        unsigned pvA = sVTp[hp][lane];
        unsigned pvB = sVTp[hp + 1][lane];
        s0 += tanh_exp2(RL(u, 2 * hp)     + bf16_lo(pvA)) * Wo[2 * hp];
        s1 += tanh_exp2(RL(u, 2 * hp + 1) + bf16_hi(pvA)) * Wo[2 * hp + 1];
        s2 += tanh_exp2(RL(u, 2 * hp + 2) + bf16_lo(pvB)) * Wo[2 * hp + 2];
        s3 += tanh_exp2(RL(u, 2 * hp + 3) + bf16_hi(pvB)) * Wo[2 * hp + 3];
    }
    const float s = (s0 + s1) + (s2 + s3);

    // histogram of valid action types (wave-private)
    int* cptr = scnt[wid];
    if (base + 0 < count) atomicAdd(&cptr[p0.x & 63], 1);
    if (base + 1 < count) atomicAdd(&cptr[p0.y & 63], 1);
    if (base + 2 < count) atomicAdd(&cptr[p0.z & 63], 1);
    if (base + 3 < count) atomicAdd(&cptr[p0.w & 63], 1);
    if (base + 4 < count) atomicAdd(&cptr[p1.x & 63], 1);
    if (base + 5 < count) atomicAdd(&cptr[p1.y & 63], 1);
    if (base + 6 < count) atomicAdd(&cptr[p1.z & 63], 1);
    if (base + 7 < count) atomicAdd(&cptr[p1.w & 63], 1);

    // softmax stats over 64 types weighted by counts
    const int cv = cptr[lane];
    float mval = (cv > 0) ? s : -3.0e38f;
    #pragma unroll
    for (int off = 32; off > 0; off >>= 1) mval = fmaxf(mval, __shfl_xor(mval, off));
    const float e  = (float)cv * __expf(s - mval);
    float se = e, sd = e * s;
    #pragma unroll
    for (int off = 32; off > 0; off >>= 1) {
        se += __shfl_xor(se, off);
        sd += __shfl_xor(sd, off);
    }
    const float logZ    = mval + __logf(se);
    const float entropy = logZ - sd / se;
    const float logp    = __shfl(s, t_star) - logZ;

    if (lane == 0) {
        out[b * 3 + 0] = logp;
        out[b * 3 + 1] = entropy;
        out[b * 3 + 2] = value;
    }
}

extern "C" void kernel_launch(void* const* d_in, const int* in_sizes, int n_in,
                              void* d_out, int out_size, void* d_ws, size_t ws_size,
                              hipStream_t stream) {
    const float* x             = (const float*)d_in[0];
    const int*   action_types  = (const int*)  d_in[1];
    const int*   action_counts = (const int*)  d_in[2];
    const int*   action        = (const int*)  d_in[3];
    const float* emb           = (const float*)d_in[4];
    const float* W1            = (const float*)d_in[5];
    const float* b1            = (const float*)d_in[6];
    const float* W2            = (const float*)d_in[7];
    const float* b2            = (const float*)d_in[8];
    const float* Wf            = (const float*)d_in[9];
    const float* We            = (const float*)d_in[10];
    const float* ba            = (const float*)d_in[11];
    const float* Wo            = (const float*)d_in[12];
    const float* bo            = (const float*)d_in[13];
    const float* Wc1           = (const float*)d_in[14];
    const float* bc1           = (const float*)d_in[15];
    const float* Wc2           = (const float*)d_in[16];
    const float* bc2           = (const float*)d_in[17];
    const float* Wc3           = (const float*)d_in[18];
    const float* bc3           = (const float*)d_in[19];
    float* out = (float*)d_out;
    unsigned char* ws = (unsigned char*)d_ws;

    k1_mfma<<<512, 256, 0, stream>>>(x, W1, Wc1, emb, We, W2, Wf, Wc2, ws);
    k2_score<<<256, 512, 0, stream>>>(ws, action_types, action_counts, action,
                                      b1, bc1, b2, ba, Wo, bo, bc2, Wc3, bc3, out);
}